// Round 11
// baseline (201.322 us; speedup 1.0000x reference)
//
#include <hip/hip_runtime.h>

#define Bsz 4
#define Nn 2048
#define Dd 256
#define Hh 4
#define HD 64
#define NTt 5
#define ETt 6
#define LOG2E 1.4426950408889634f
#define MSUB 24.0f
#define SCLQ 0.18033688011112042f   // 0.125 * LOG2E, folded into Q at qkv time

typedef float f32x4 __attribute__((ext_vector_type(4)));
typedef __bf16 bf16x8 __attribute__((ext_vector_type(8)));
typedef unsigned int u32x4 __attribute__((ext_vector_type(4)));
typedef short s16x4 __attribute__((ext_vector_type(4)));
typedef unsigned short u16;
typedef unsigned char u8;
typedef unsigned int uint;

static __device__ __forceinline__ u16 f2bf(float f) {
  unsigned int u = __builtin_bit_cast(unsigned int, f);
  u = (u + 0x7fffu + ((u >> 16) & 1u)) >> 16;
  return (u16)u;
}

static __device__ __forceinline__ bf16x8 ld8(const u16* p) {
  return __builtin_bit_cast(bf16x8, *(const u32x4*)p);
}

// async global->LDS, 16B per lane; LDS dest = wave-uniform base + lane*16
static __device__ __forceinline__ void stage16(const void* g, void* l) {
  __builtin_amdgcn_global_load_lds(
      (const __attribute__((address_space(1))) uint*)g,
      (__attribute__((address_space(3))) uint*)l, 16, 0, 0);
}

#define MFMA16(a, b, c) __builtin_amdgcn_mfma_f32_16x16x32_bf16((a), (b), (c), 0, 0, 0)

// ---------------- ws layout (bytes) ----------------
#define OFF_X      0u            // f32  [8192][256]        8388608
#define OFF_XBF    8388608u      // bf16 [8192][256]        4194304
#define OFF_WQKVT  12582912u     // bf16 [768][256]         393216
#define OFF_WOT    12976128u     // bf16 [256][256]         131072
#define OFF_BQKV   13107200u     // f32  [768]              3072
#define OFF_Q      13110272u     // bf16 [B,H,N,64]         4194304
#define OFF_K      17304576u     // bf16 [B,H,N,64]         4194304
#define OFF_VT     25693184u     // bf16 [B,H,64,N]         4194304
#define OFF_CTX    29887488u     // bf16 [8192][256]        4194304
#define OFF_CODES  34081792u     // u8   [B,128,32,64,16]   16777216

// ================= pack weights (transposed, bf16) =================
__global__ void pack_kernel(const float* Wq, const float* Wk, const float* Wv,
                            const float* Wo, const float* bq, const float* bk,
                            const float* bv, u16* wqkvT, u16* woT, float* bqkv) {
  int tid = blockIdx.x * 256 + threadIdx.x;
  if (tid < 196608) {                 // WqkvT[c][k] = W_which[k][cc]
    int c = tid >> 8, k = tid & 255;
    int which = c >> 8, cc = c & 255;
    const float* W = (which == 0) ? Wq : ((which == 1) ? Wk : Wv);
    wqkvT[tid] = f2bf(W[k * 256 + cc]);
  } else if (tid < 262144) {          // WoT[c][k] = Wo[k][c]
    int t2 = tid - 196608;
    int c = t2 >> 8, k = t2 & 255;
    woT[t2] = f2bf(Wo[k * 256 + c]);
  } else if (tid < 262912) {
    int c = tid - 262144;
    int which = c >> 8, cc = c & 255;
    bqkv[c] = (which == 0) ? bq[cc] : ((which == 1) ? bk[cc] : bv[cc]);
  }
}

// ================= x = nodes + node_type_embed[nt] =================
__global__ void embed_kernel(const float* nodes, const int* node_types,
                             const float* nte, float* xf, u16* xbf) {
  int t = blockIdx.x * 256 + threadIdx.x;    // 524288 threads, 4 floats each
  int flat = t * 4;
  int bn = flat >> 8, d0 = flat & 255;
  int nt = node_types[bn];
  float4 nv = *(const float4*)(nodes + flat);
  float4 ev = *(const float4*)(nte + nt * 256 + d0);
  float4 x4;
  x4.x = nv.x + ev.x; x4.y = nv.y + ev.y; x4.z = nv.z + ev.z; x4.w = nv.w + ev.w;
  *(float4*)(xf + flat) = x4;
  ushort4 xb;
  xb.x = f2bf(x4.x); xb.y = f2bf(x4.y); xb.z = f2bf(x4.z); xb.w = f2bf(x4.w);
  *(ushort4*)(xbf + flat) = xb;
}

// ================= mask pack: code = (et + 6*tm + 12*adj)*4 ===============
// TRANSPOSED fragment order for swapped-operand QK^T:
// codes[b][qt16][kt][lane][word ks][byte j] covers
//   q = qt*16 + (lane&15), kcol = kt*64 + ks*16 + (lane>>4)*4 + j
__global__ __launch_bounds__(256) void maskpack_kernel(
    const int* node_types, const int* edge_types, const float* adjacency,
    u8* codes) {
  int t = blockIdx.x * 256 + threadIdx.x;   // 1048576
  int lane = t & 63;
  int kt = (t >> 6) & 31;
  int qt = (t >> 11) & 127;
  int b = t >> 18;
  int l15 = lane & 15, l4 = lane >> 4;
  const int* etb = edge_types + (size_t)b * Nn * Nn;
  const float* adjb = adjacency + (size_t)b * Nn * Nn;
  const int* ntb = node_types + b * Nn;
  int qrow = qt * 16 + l15;
  int ntq = ntb[qrow];
  const int* etr = etb + (size_t)qrow * Nn;
  const float* adr = adjb + (size_t)qrow * Nn;
  unsigned int wds[4];
#pragma unroll
  for (int ks = 0; ks < 4; ++ks) {
    int k0 = kt * 64 + ks * 16 + l4 * 4;
    int4 et4 = *(const int4*)(etr + k0);
    float4 a4 = *(const float4*)(adr + k0);
    int4 nt4 = *(const int4*)(ntb + k0);
    int e[4] = {et4.x, et4.y, et4.z, et4.w};
    int n[4] = {nt4.x, nt4.y, nt4.z, nt4.w};
    float a[4] = {a4.x, a4.y, a4.z, a4.w};
    unsigned int acc = 0;
#pragma unroll
    for (int j = 0; j < 4; ++j) {
      int code = e[j] + ((ntq == n[j]) ? 6 : 0) + ((a[j] != 0.0f) ? 12 : 0);
      acc |= (unsigned int)(code * 4) << (8 * j);
    }
    wds[ks] = acc;
  }
  u32x4 out = {wds[0], wds[1], wds[2], wds[3]};
  *(u32x4*)(codes + (size_t)t * 16) = out;
}

// ================= QKV GEMM: [8192,256] @ [256,768] =================
// Q pre-scaled by 0.125*LOG2E (f32, before bf16 round); V written TRANSPOSED
// directly to Vtb[B,H,64,N] (vtrans kernel eliminated).
__global__ __launch_bounds__(256) void qkv_kernel(const u16* xbf, const u16* wqkvT,
                                                  const float* bqkv,
                                                  u16* Qb, u16* Kb, u16* Vtb) {
  int cb = blockIdx.x;              // 0..11
  int rb = blockIdx.y;              // 0..127
  int w = threadIdx.x >> 6, lane = threadIdx.x & 63;
  int l15 = lane & 15, l4 = lane >> 4;
  int row0 = rb * 64 + w * 16;
  int col0 = cb * 64;
  const u16* xr = xbf + (size_t)(row0 + l15) * 256;
  f32x4 acc[4];
#pragma unroll
  for (int i = 0; i < 4; ++i) acc[i] = (f32x4){0.f, 0.f, 0.f, 0.f};
#pragma unroll
  for (int kst = 0; kst < 8; ++kst) {
    int k0 = kst * 32 + l4 * 8;
    bf16x8 a = ld8(xr + k0);
#pragma unroll
    for (int cs = 0; cs < 4; ++cs) {
      int col = col0 + cs * 16 + l15;
      bf16x8 bw = ld8(wqkvT + (size_t)col * 256 + k0);
      acc[cs] = MFMA16(a, bw, acc[cs]);
    }
  }
#pragma unroll
  for (int cs = 0; cs < 4; ++cs) {
    int col = col0 + cs * 16 + l15;
    float bias = bqkv[col];
    int which = col >> 8, c = col & 255;
    int h = c >> 6, hd = c & 63;
    float scale = (which == 0) ? SCLQ : 1.0f;
#pragma unroll
    for (int j = 0; j < 4; ++j) {
      int row = row0 + l4 * 4 + j;
      int bb = row >> 11, n = row & 2047;
      u16 val = f2bf((acc[cs][j] + bias) * scale);
      if (which == 2)
        Vtb[((size_t)((bb * Hh + h) * HD + hd)) * Nn + n] = val;
      else if (which == 0)
        Qb[(size_t)(((bb * Hh + h) * Nn + n)) * HD + hd] = val;
      else
        Kb[(size_t)(((bb * Hh + h) * Nn + n)) * HD + hd] = val;
    }
  }
}

// ================= attention =================
// block = (b, h, 64-row q-tile): 512 blocks x 4 waves (16 rows each).
// BK=128: each iteration covers 128 k-cols (2 kt), ONE barrier per iteration
// (32 barriers total vs 64). K chunks [128n x 64hd] (128B rows) and V chunks
// [64d x 128n] (256B rows) double-buffered in LDS, XOR-swizzled source+read.
// Counted vmcnt leaves codes prefetch (+8 attn stores in pass 2) in flight.
// Swapped-operand QK^T with bias-LUT-as-C-init (bpermute); fixed-max softmax.
// s_setprio(1) around the MFMA/exp2 cluster (inter-block arbitration).
__global__ __launch_bounds__(256) void attn_kernel(
    const u16* Qb, const u16* Kb, const u16* Vtb, const u8* codes,
    const float* ee_g, float* attn_out, u16* ctx_ws) {
  __shared__ __align__(16) char kls[2][16384];
  __shared__ __align__(16) char vls[2][16384];
  __shared__ __align__(16) char pls[4][4096];

  int bid0 = blockIdx.x;
  int bid = ((bid0 & 7) << 6) | (bid0 >> 3);   // XCD-chunked swizzle (512 wgs)
  int qt64 = bid & 31;
  int h = (bid >> 5) & 3;
  int b = bid >> 7;
  int w = threadIdx.x >> 6, lane = threadIdx.x & 63;
  int l15 = lane & 15, l4 = lane >> 4;
  int q0 = qt64 * 64 + w * 16;
  int bh = b * Hh + h;

  // 24-entry bias LUT (log2 domain, MSUB folded in), one value per lane 0..23
  float lutv = 0.f;
  {
    int ln = lane;
    int et = ln - 6 * (ln / 6);
    int tm = (ln / 6) & 1;
    int adj = ln / 12;
    if (ln < 24)
      lutv = (ee_g[et * Hh + h] + (tm ? 0.10f : -0.05f)) * LOG2E +
             (adj ? 0.f : -1.442695041e9f) - MSUB;
  }
  int lut_i = __float_as_int(lutv);

  // Q as B-fragment (pre-scaled by SCLQ in qkv_kernel)
  const u16* Qp = Qb + (size_t)(bh * Nn + q0 + l15) * HD;
  bf16x8 bq0 = ld8(Qp + l4 * 8);
  bf16x8 bq1 = ld8(Qp + 32 + l4 * 8);

  const char* Kg = (const char*)(Kb + (size_t)bh * Nn * HD);
  const char* Vg = (const char*)(Vtb + (size_t)bh * HD * Nn);
  const u32x4* cp = (const u32x4*)codes + ((size_t)(b * 128 + (q0 >> 4)) * 32) * 64;

  // staging: LDS[o] = G[row(o)*stride + (o ^ ((row&7)<<4)) & rowmask]
  // per wave 4 slices: o = w*4096 + j*1024 + lane*16
  int oS[4];
  const char* KgS[4];
  const char* VgS[4];
#pragma unroll
  for (int j = 0; j < 4; ++j) {
    int o = w * 4096 + j * 1024 + lane * 16;
    oS[j] = o;
    int rowK = o >> 7;                       // 128B rows (K: [n][64]bf16)
    int swK = (o ^ ((rowK & 7) << 4)) & 127;
    KgS[j] = Kg + (size_t)rowK * 128 + swK;
    int rowV = o >> 8;                       // 256B rows (V: [d][128]bf16 chunk)
    int swV = (o ^ ((rowV & 7) << 4)) & 255;
    VgS[j] = Vg + (size_t)rowV * (Nn * 2) + swV;
  }

  // swizzled ds_read bases
  int sw = (l15 & 7) << 4;
  int raK = (l15 * 128 + l4 * 16) ^ sw;      // + ks8*2048, ^64 for hd 32-63
  int pwbase = l15 * 256;

  // ---------- pass 1: accumulate exp2 sums ----------
#pragma unroll
  for (int j = 0; j < 4; ++j) stage16(KgS[j], (char*)kls + oS[j]);
  __builtin_amdgcn_sched_barrier(0);
  u32x4 cwA = cp[lane];
  u32x4 cwB = cp[64 + lane];
  __builtin_amdgcn_sched_barrier(0);
  asm volatile("s_waitcnt vmcnt(2) lgkmcnt(0)" ::: "memory");
  __builtin_amdgcn_s_barrier();

  float accl = 0.f;
#pragma unroll 1
  for (int i = 0; i < 16; ++i) {
    int cb = i & 1, nb = cb ^ 1;
    u32x4 cwAn = cwA, cwBn = cwB;
    if (i < 15) {
      const char* Kn = Kg + (size_t)(i + 1) * 16384;
#pragma unroll
      for (int j = 0; j < 4; ++j)
        stage16(KgS[j] + (size_t)(i + 1) * 16384, (char*)kls + nb * 16384 + oS[j]);
      __builtin_amdgcn_sched_barrier(0);
      cwAn = cp[(2 * i + 2) * 64 + lane];
      cwBn = cp[(2 * i + 3) * 64 + lane];
      __builtin_amdgcn_sched_barrier(0);
      (void)Kn;
    }
    const char* kcur = (const char*)kls + cb * 16384;
    __builtin_amdgcn_s_setprio(1);
#pragma unroll
    for (int ks = 0; ks < 8; ++ks) {
      unsigned int cword = (ks < 4) ? cwA[ks] : cwB[ks - 4];
      f32x4 acc;
#pragma unroll
      for (int j = 0; j < 4; ++j)
        acc[j] = __int_as_float(
            __builtin_amdgcn_ds_bpermute((cword >> (8 * j)) & 0xFF, lut_i));
      acc = MFMA16(ld8((const u16*)(kcur + raK + ks * 2048)), bq0, acc);
      acc = MFMA16(ld8((const u16*)(kcur + (raK ^ 64) + ks * 2048)), bq1, acc);
      accl += (__builtin_amdgcn_exp2f(acc[0]) + __builtin_amdgcn_exp2f(acc[1])) +
              (__builtin_amdgcn_exp2f(acc[2]) + __builtin_amdgcn_exp2f(acc[3]));
    }
    __builtin_amdgcn_s_setprio(0);
    if (i < 15) {
      asm volatile("s_waitcnt vmcnt(2) lgkmcnt(0)" ::: "memory");
      __builtin_amdgcn_s_barrier();
    }
    cwA = cwAn;
    cwB = cwBn;
  }
  accl += __shfl_xor(accl, 16);
  accl += __shfl_xor(accl, 32);
  bool zrow = (accl == 0.0f);
  float pscale = zrow ? 0.0f : 1.0f / accl;
  float pbias = zrow ? (1.0f / 2048.0f) : 0.0f;

  __syncthreads();   // all waves done reading kls before pass-2 restaging

  // ---------- pass 2: write attn, accumulate PV ----------
  float* attb = attn_out + (size_t)bh * Nn * Nn + (size_t)(q0 + l15) * Nn;
  char* pwave = (char*)pls + w * 4096;
  f32x4 ctx[4];
#pragma unroll
  for (int i = 0; i < 4; ++i) ctx[i] = (f32x4){0.f, 0.f, 0.f, 0.f};

#pragma unroll
  for (int j = 0; j < 4; ++j) {
    stage16(KgS[j], (char*)kls + oS[j]);
    stage16(VgS[j], (char*)vls + oS[j]);
  }
  __builtin_amdgcn_sched_barrier(0);
  cwA = cp[lane];
  cwB = cp[64 + lane];
  __builtin_amdgcn_sched_barrier(0);
  asm volatile("s_waitcnt vmcnt(2) lgkmcnt(0)" ::: "memory");
  __builtin_amdgcn_s_barrier();

#pragma unroll 1
  for (int i = 0; i < 16; ++i) {
    int cb = i & 1, nb = cb ^ 1;
    u32x4 cwAn = cwA, cwBn = cwB;
    if (i < 15) {
#pragma unroll
      for (int j = 0; j < 4; ++j) {
        stage16(KgS[j] + (size_t)(i + 1) * 16384, (char*)kls + nb * 16384 + oS[j]);
        stage16(VgS[j] + (size_t)(i + 1) * 256, (char*)vls + nb * 16384 + oS[j]);
      }
      __builtin_amdgcn_sched_barrier(0);
      cwAn = cp[(2 * i + 2) * 64 + lane];
      cwBn = cp[(2 * i + 3) * 64 + lane];
      __builtin_amdgcn_sched_barrier(0);
    }
    const char* kcur = (const char*)kls + cb * 16384;
    const char* vcur = (const char*)vls + cb * 16384;
    __builtin_amdgcn_s_setprio(1);
#pragma unroll
    for (int ks = 0; ks < 8; ++ks) {
      unsigned int cword = (ks < 4) ? cwA[ks] : cwB[ks - 4];
      f32x4 acc;
#pragma unroll
      for (int j = 0; j < 4; ++j)
        acc[j] = __int_as_float(
            __builtin_amdgcn_ds_bpermute((cword >> (8 * j)) & 0xFF, lut_i));
      acc = MFMA16(ld8((const u16*)(kcur + raK + ks * 2048)), bq0, acc);
      acc = MFMA16(ld8((const u16*)(kcur + (raK ^ 64) + ks * 2048)), bq1, acc);
      f32x4 p;
#pragma unroll
      for (int j = 0; j < 4; ++j)
        p[j] = __builtin_amdgcn_exp2f(acc[j]) * pscale + pbias;
      __builtin_nontemporal_store(p, (f32x4*)(attb + i * 128 + ks * 16 + l4 * 4));
      s16x4 pb;
#pragma unroll
      for (int j = 0; j < 4; ++j)
        pb[j] = (short)__builtin_bit_cast(u16, (__bf16)p[j]);
      *(s16x4*)(pwave + pwbase + ((ks * 32 + l4 * 8) ^ sw)) = pb;
    }
    // PV: read P as A-fragments (4 windows of 32 k), V as B-fragments
#pragma unroll
    for (int ks4 = 0; ks4 < 4; ++ks4) {
      bf16x8 pa = ld8((const u16*)(pwave + pwbase + ((ks4 * 64 + l4 * 16) ^ sw)));
#pragma unroll
      for (int ds_ = 0; ds_ < 4; ++ds_) {
        bf16x8 v = ld8((const u16*)(vcur + ds_ * 4096 + l15 * 256 +
                                    ((ks4 * 64 + l4 * 16) ^ sw)));
        ctx[ds_] = MFMA16(pa, v, ctx[ds_]);
      }
    }
    __builtin_amdgcn_s_setprio(0);
    // drain this iter's 8 stages; leave codes(2) + 8 attn stores in flight
    if (i < 15) {
      asm volatile("s_waitcnt vmcnt(10) lgkmcnt(0)" ::: "memory");
      __builtin_amdgcn_s_barrier();
    }
    cwA = cwAn;
    cwB = cwBn;
  }

#pragma unroll
  for (int ds_ = 0; ds_ < 4; ++ds_) {
    int col = h * 64 + ds_ * 16 + l15;
#pragma unroll
    for (int j = 0; j < 4; ++j) {
      int qrow = q0 + l4 * 4 + j;
      ctx_ws[(size_t)(b * Nn + qrow) * Dd + col] = f2bf(ctx[ds_][j]);
    }
  }
}

// ================= out GEMM + residual + LayerNorm =================
__global__ __launch_bounds__(256) void outln_kernel(const u16* ctxb, const u16* woT,
                                                    const float* bo, const float* xf,
                                                    const float* ln_g, const float* ln_b,
                                                    float* yout) {
  __shared__ float ytile[32][257];
  __shared__ float muS[32], rvS[32];
  int bm0 = blockIdx.x * 32;
  int w = threadIdx.x >> 6, lane = threadIdx.x & 63;
  int l15 = lane & 15, l4 = lane >> 4;
  f32x4 acc[2][4];
#pragma unroll
  for (int q = 0; q < 2; ++q)
#pragma unroll
    for (int i = 0; i < 4; ++i) acc[q][i] = (f32x4){0.f, 0.f, 0.f, 0.f};
#pragma unroll
  for (int kst = 0; kst < 8; ++kst) {
    int k0 = kst * 32 + l4 * 8;
    bf16x8 a0 = ld8(ctxb + (size_t)(bm0 + l15) * 256 + k0);
    bf16x8 a1 = ld8(ctxb + (size_t)(bm0 + 16 + l15) * 256 + k0);
#pragma unroll
    for (int ds_ = 0; ds_ < 4; ++ds_) {
      bf16x8 bw = ld8(woT + (size_t)(w * 64 + ds_ * 16 + l15) * 256 + k0);
      acc[0][ds_] = MFMA16(a0, bw, acc[0][ds_]);
      acc[1][ds_] = MFMA16(a1, bw, acc[1][ds_]);
    }
  }
#pragma unroll
  for (int qs = 0; qs < 2; ++qs)
#pragma unroll
    for (int ds_ = 0; ds_ < 4; ++ds_) {
      int col = w * 64 + ds_ * 16 + l15;
      float bof = bo[col];
#pragma unroll
      for (int j = 0; j < 4; ++j) {
        int row = qs * 16 + l4 * 4 + j;
        ytile[row][col] = acc[qs][ds_][j] + bof + xf[(size_t)(bm0 + row) * 256 + col];
      }
    }
  __syncthreads();
  int row = threadIdx.x >> 3, seg = threadIdx.x & 7;
  float ps = 0.f, pq = 0.f;
#pragma unroll
  for (int c = 0; c < 32; ++c) {
    float v = ytile[row][seg * 32 + c];
    ps += v; pq += v * v;
  }
  ps += __shfl_xor(ps, 1); pq += __shfl_xor(pq, 1);
  ps += __shfl_xor(ps, 2); pq += __shfl_xor(pq, 2);
  ps += __shfl_xor(ps, 4); pq += __shfl_xor(pq, 4);
  if (seg == 0) {
    float mu = ps * (1.0f / 256.0f);
    muS[row] = mu;
    rvS[row] = rsqrtf(pq * (1.0f / 256.0f) - mu * mu + 1e-5f);
  }
  __syncthreads();
  float mu = muS[row], rv = rvS[row];
  float* yr = yout + (size_t)(bm0 + row) * 256;
#pragma unroll
  for (int c0 = 0; c0 < 32; c0 += 4) {
    int c = seg * 32 + c0;
    float4 o;
    o.x = (ytile[row][c + 0] - mu) * rv * ln_g[c + 0] + ln_b[c + 0];
    o.y = (ytile[row][c + 1] - mu) * rv * ln_g[c + 1] + ln_b[c + 1];
    o.z = (ytile[row][c + 2] - mu) * rv * ln_g[c + 2] + ln_b[c + 2];
    o.w = (ytile[row][c + 3] - mu) * rv * ln_g[c + 3] + ln_b[c + 3];
    *(float4*)(yr + c) = o;
  }
}

extern "C" void kernel_launch(void* const* d_in, const int* in_sizes, int n_in,
                              void* d_out, int out_size, void* d_ws, size_t ws_size,
                              hipStream_t stream) {
  const float* nodes = (const float*)d_in[0];
  const int* node_types = (const int*)d_in[1];
  const int* edge_types = (const int*)d_in[2];
  const float* adjacency = (const float*)d_in[3];
  const float* nte = (const float*)d_in[4];
  const float* ee = (const float*)d_in[5];
  const float* Wq = (const float*)d_in[6];
  const float* bq = (const float*)d_in[7];
  const float* Wk = (const float*)d_in[8];
  const float* bk = (const float*)d_in[9];
  const float* Wv = (const float*)d_in[10];
  const float* bv = (const float*)d_in[11];
  const float* Wo = (const float*)d_in[12];
  const float* bo = (const float*)d_in[13];
  const float* ln_g = (const float*)d_in[14];
  const float* ln_b = (const float*)d_in[15];

  float* y = (float*)d_out;
  float* attn = y + (size_t)Bsz * Nn * Dd;

  char* ws = (char*)d_ws;
  float* xf = (float*)(ws + OFF_X);
  u16* xbf = (u16*)(ws + OFF_XBF);
  u16* wqkvT = (u16*)(ws + OFF_WQKVT);
  u16* woT = (u16*)(ws + OFF_WOT);
  float* bqkv = (float*)(ws + OFF_BQKV);
  u16* Qb = (u16*)(ws + OFF_Q);
  u16* Kb = (u16*)(ws + OFF_K);
  u16* Vtb = (u16*)(ws + OFF_VT);
  u16* ctxb = (u16*)(ws + OFF_CTX);
  u8* codes = (u8*)(ws + OFF_CODES);

  pack_kernel<<<1027, 256, 0, stream>>>(Wq, Wk, Wv, Wo, bq, bk, bv, wqkvT, woT, bqkv);
  embed_kernel<<<2048, 256, 0, stream>>>(nodes, node_types, nte, xf, xbf);
  maskpack_kernel<<<4096, 256, 0, stream>>>(node_types, edge_types, adjacency, codes);
  qkv_kernel<<<dim3(12, 128), 256, 0, stream>>>(xbf, wqkvT, bqkv, Qb, Kb, Vtb);
  attn_kernel<<<512, 256, 0, stream>>>(Qb, Kb, Vtb, codes, ee, attn, ctxb);
  outln_kernel<<<256, 256, 0, stream>>>(ctxb, woT, bo, xf, ln_g, ln_b, y);
}

// Round 12
// 185.175 us; speedup vs baseline: 1.0872x; 1.0872x over previous
//
#include <hip/hip_runtime.h>

#define Bsz 4
#define Nn 2048
#define Dd 256
#define Hh 4
#define HD 64
#define NTt 5
#define ETt 6
#define LOG2E 1.4426950408889634f
#define MSUB 24.0f
#define SCLQ 0.18033688011112042f   // 0.125 * LOG2E, folded into Q at qkv time

typedef float f32x4 __attribute__((ext_vector_type(4)));
typedef __bf16 bf16x8 __attribute__((ext_vector_type(8)));
typedef unsigned int u32x4 __attribute__((ext_vector_type(4)));
typedef unsigned short u16;
typedef unsigned char u8;
typedef unsigned int uint;

static __device__ __forceinline__ u16 f2bf(float f) {
  unsigned int u = __builtin_bit_cast(unsigned int, f);
  u = (u + 0x7fffu + ((u >> 16) & 1u)) >> 16;
  return (u16)u;
}

static __device__ __forceinline__ bf16x8 ld8(const u16* p) {
  return __builtin_bit_cast(bf16x8, *(const u32x4*)p);
}

// async global->LDS, 16B per lane; LDS dest = wave-uniform base + lane*16
static __device__ __forceinline__ void stage16(const void* g, void* l) {
  __builtin_amdgcn_global_load_lds(
      (const __attribute__((address_space(1))) uint*)g,
      (__attribute__((address_space(3))) uint*)l, 16, 0, 0);
}

#define MFMA16(a, b, c) __builtin_amdgcn_mfma_f32_16x16x32_bf16((a), (b), (c), 0, 0, 0)

// ---------------- ws layout (bytes) ----------------
#define OFF_X      0u            // f32  [8192][256]        8388608
#define OFF_XBF    8388608u      // bf16 [8192][256]        4194304
#define OFF_WQKVT  12582912u     // bf16 [768][256]         393216
#define OFF_WOT    12976128u     // bf16 [256][256]         131072
#define OFF_BQKV   13107200u     // f32  [768]              3072
#define OFF_Q      13110272u     // bf16 [B,H,N,64]         4194304
#define OFF_K      17304576u     // bf16 [B,H,N,64]         4194304
#define OFF_VT     25693184u     // bf16 [B,H,64,N]         4194304
#define OFF_CTX    29887488u     // bf16 [8192][256]        4194304
#define OFF_CODES  34081792u     // u8   [B,128,32,64,16]   16777216

// ================= pack weights (transposed, bf16) =================
__global__ void pack_kernel(const float* Wq, const float* Wk, const float* Wv,
                            const float* Wo, const float* bq, const float* bk,
                            const float* bv, u16* wqkvT, u16* woT, float* bqkv) {
  int tid = blockIdx.x * 256 + threadIdx.x;
  if (tid < 196608) {                 // WqkvT[c][k] = W_which[k][cc]
    int c = tid >> 8, k = tid & 255;
    int which = c >> 8, cc = c & 255;
    const float* W = (which == 0) ? Wq : ((which == 1) ? Wk : Wv);
    wqkvT[tid] = f2bf(W[k * 256 + cc]);
  } else if (tid < 262144) {          // WoT[c][k] = Wo[k][c]
    int t2 = tid - 196608;
    int c = t2 >> 8, k = t2 & 255;
    woT[t2] = f2bf(Wo[k * 256 + c]);
  } else if (tid < 262912) {
    int c = tid - 262144;
    int which = c >> 8, cc = c & 255;
    bqkv[c] = (which == 0) ? bq[cc] : ((which == 1) ? bk[cc] : bv[cc]);
  }
}

// ================= x = nodes + node_type_embed[nt] =================
__global__ void embed_kernel(const float* nodes, const int* node_types,
                             const float* nte, float* xf, u16* xbf) {
  int t = blockIdx.x * 256 + threadIdx.x;    // 524288 threads, 4 floats each
  int flat = t * 4;
  int bn = flat >> 8, d0 = flat & 255;
  int nt = node_types[bn];
  float4 nv = *(const float4*)(nodes + flat);
  float4 ev = *(const float4*)(nte + nt * 256 + d0);
  float4 x4;
  x4.x = nv.x + ev.x; x4.y = nv.y + ev.y; x4.z = nv.z + ev.z; x4.w = nv.w + ev.w;
  *(float4*)(xf + flat) = x4;
  ushort4 xb;
  xb.x = f2bf(x4.x); xb.y = f2bf(x4.y); xb.z = f2bf(x4.z); xb.w = f2bf(x4.w);
  *(ushort4*)(xbf + flat) = xb;
}

// ================= mask pack: code = (et + 6*tm + 12*adj)*4 ===============
// TRANSPOSED fragment order for swapped-operand QK^T:
// codes[b][qt16][kt][lane][word ks][byte j] covers
//   q = qt*16 + (lane&15), kcol = kt*64 + ks*16 + (lane>>4)*4 + j
__global__ __launch_bounds__(256) void maskpack_kernel(
    const int* node_types, const int* edge_types, const float* adjacency,
    u8* codes) {
  int t = blockIdx.x * 256 + threadIdx.x;   // 1048576
  int lane = t & 63;
  int kt = (t >> 6) & 31;
  int qt = (t >> 11) & 127;
  int b = t >> 18;
  int l15 = lane & 15, l4 = lane >> 4;
  const int* etb = edge_types + (size_t)b * Nn * Nn;
  const float* adjb = adjacency + (size_t)b * Nn * Nn;
  const int* ntb = node_types + b * Nn;
  int qrow = qt * 16 + l15;
  int ntq = ntb[qrow];
  const int* etr = etb + (size_t)qrow * Nn;
  const float* adr = adjb + (size_t)qrow * Nn;
  unsigned int wds[4];
#pragma unroll
  for (int ks = 0; ks < 4; ++ks) {
    int k0 = kt * 64 + ks * 16 + l4 * 4;
    int4 et4 = *(const int4*)(etr + k0);
    float4 a4 = *(const float4*)(adr + k0);
    int4 nt4 = *(const int4*)(ntb + k0);
    int e[4] = {et4.x, et4.y, et4.z, et4.w};
    int n[4] = {nt4.x, nt4.y, nt4.z, nt4.w};
    float a[4] = {a4.x, a4.y, a4.z, a4.w};
    unsigned int acc = 0;
#pragma unroll
    for (int j = 0; j < 4; ++j) {
      int code = e[j] + ((ntq == n[j]) ? 6 : 0) + ((a[j] != 0.0f) ? 12 : 0);
      acc |= (unsigned int)(code * 4) << (8 * j);
    }
    wds[ks] = acc;
  }
  u32x4 out = {wds[0], wds[1], wds[2], wds[3]};
  *(u32x4*)(codes + (size_t)t * 16) = out;
}

// ================= QKV GEMM: [8192,256] @ [256,768] =================
// Q pre-scaled by 0.125*LOG2E (f32, before bf16 round); V written TRANSPOSED
// directly to Vtb[B,H,64,N].
__global__ __launch_bounds__(256) void qkv_kernel(const u16* xbf, const u16* wqkvT,
                                                  const float* bqkv,
                                                  u16* Qb, u16* Kb, u16* Vtb) {
  int cb = blockIdx.x;              // 0..11
  int rb = blockIdx.y;              // 0..127
  int w = threadIdx.x >> 6, lane = threadIdx.x & 63;
  int l15 = lane & 15, l4 = lane >> 4;
  int row0 = rb * 64 + w * 16;
  int col0 = cb * 64;
  const u16* xr = xbf + (size_t)(row0 + l15) * 256;
  f32x4 acc[4];
#pragma unroll
  for (int i = 0; i < 4; ++i) acc[i] = (f32x4){0.f, 0.f, 0.f, 0.f};
#pragma unroll
  for (int kst = 0; kst < 8; ++kst) {
    int k0 = kst * 32 + l4 * 8;
    bf16x8 a = ld8(xr + k0);
#pragma unroll
    for (int cs = 0; cs < 4; ++cs) {
      int col = col0 + cs * 16 + l15;
      bf16x8 bw = ld8(wqkvT + (size_t)col * 256 + k0);
      acc[cs] = MFMA16(a, bw, acc[cs]);
    }
  }
#pragma unroll
  for (int cs = 0; cs < 4; ++cs) {
    int col = col0 + cs * 16 + l15;
    float bias = bqkv[col];
    int which = col >> 8, c = col & 255;
    int h = c >> 6, hd = c & 63;
    float scale = (which == 0) ? SCLQ : 1.0f;
#pragma unroll
    for (int j = 0; j < 4; ++j) {
      int row = row0 + l4 * 4 + j;
      int bb = row >> 11, n = row & 2047;
      u16 val = f2bf((acc[cs][j] + bias) * scale);
      if (which == 2)
        Vtb[((size_t)((bb * Hh + h) * HD + hd)) * Nn + n] = val;
      else if (which == 0)
        Qb[(size_t)(((bb * Hh + h) * Nn + n)) * HD + hd] = val;
      else
        Kb[(size_t)(((bb * Hh + h) * Nn + n)) * HD + hd] = val;
    }
  }
}

// ================= attention: single-QK^T k-split =================
// block = (b, h, 16-row q-tile): 2048 blocks x 4 waves; wave w owns k-range
// [w*512, w*512+512) = 8 kt of 64. QK^T+bias+exp2 computed ONCE (pass 1),
// packed to bf16 in registers (p[8][8] u32, fully unrolled). Row sums combined
// via tiny LDS. Pass 2: attn store = float(p)*cscale; PV uses UNNORMALIZED p,
// ctx scaled per-row afterwards. K/V staged into wave-PRIVATE LDS dbuf via
// global_load_lds with counted vmcnt — ZERO barriers in the main loops.
__global__ __launch_bounds__(256) void attn_kernel(
    const u16* Qb, const u16* Kb, const u16* Vtb, const u8* codes,
    const float* ee_g, float* attn_out, u16* ctx_ws) {
  __shared__ __align__(16) char kvb[4][2][8192];   // per-wave K(p1)/V(p2) dbuf
  __shared__ __align__(16) char pls[4][2048];      // per-wave P roundtrip
  __shared__ float lsh[4][16];

  int bid0 = blockIdx.x;
  int bid = ((bid0 & 7) << 8) | (bid0 >> 3);   // XCD-chunked (2048 % 8 == 0)
  int qt = bid & 127;
  int h = (bid >> 7) & 3;
  int b = bid >> 9;
  int w = threadIdx.x >> 6, lane = threadIdx.x & 63;
  int l15 = lane & 15, l4 = lane >> 4;
  int q0 = qt * 16;
  int bh = b * Hh + h;
  int wk0 = w * 512;                 // this wave's k-range start

  // 24-entry bias LUT (log2 domain, MSUB folded in), one value per lane 0..23
  float lutv = 0.f;
  {
    int ln = lane;
    int et = ln - 6 * (ln / 6);
    int tm = (ln / 6) & 1;
    int adj = ln / 12;
    if (ln < 24)
      lutv = (ee_g[et * Hh + h] + (tm ? 0.10f : -0.05f)) * LOG2E +
             (adj ? 0.f : -1.442695041e9f) - MSUB;
  }
  int lut_i = __float_as_int(lutv);

  // Q as B-fragment (pre-scaled by SCLQ in qkv_kernel)
  const u16* Qp = Qb + (size_t)(bh * Nn + q0 + l15) * HD;
  bf16x8 bq0 = ld8(Qp + l4 * 8);
  bf16x8 bq1 = ld8(Qp + 32 + l4 * 8);

  const char* Kgw = (const char*)(Kb + (size_t)bh * Nn * HD) + (size_t)wk0 * 128;
  const char* Vg = (const char*)(Vtb + (size_t)bh * HD * Nn);
  const u32x4* cp = (const u32x4*)codes + ((size_t)(b * 128 + qt) * 32) * 64;

  // staging: 8KB tile = 64 rows x 128B; LDS[o] = G[row*stride + swz(o)&127]
  int oS[8];
  const char* KgS[8];
  const char* VgS[8];
#pragma unroll
  for (int j = 0; j < 8; ++j) {
    int o = j * 1024 + lane * 16;
    oS[j] = o;
    int row = o >> 7;
    int sz = (o ^ ((row & 7) << 4)) & 127;
    KgS[j] = Kgw + (size_t)row * 128 + sz;                 // + kt*8192
    VgS[j] = Vg + (size_t)row * (Nn * 2) + wk0 * 2 + sz;   // + kt*128
  }
  char* myb0 = (char*)kvb[w][0];
  char* myb1 = (char*)kvb[w][1];

  int sw = (l15 & 7) << 4;
  int ra = (l15 * 128 + l4 * 16) ^ sw;
  char* pwave = (char*)pls[w];
  int pwbase = l15 * 128;

  uint p[8][8];                      // bf16x2 packed exp2 values (C-layout)
  float accl = 0.f;

  // ---------- pass 1: QK^T + bias + exp2, once ----------
#pragma unroll
  for (int j = 0; j < 8; ++j) stage16(KgS[j], myb0 + oS[j]);
  u32x4 cw = cp[(size_t)(w * 8) * 64 + lane];

#pragma unroll
  for (int i = 0; i < 8; ++i) {
    u32x4 cwn = cw;
    if (i < 7) {
      char* nb = (i & 1) ? myb0 : myb1;
#pragma unroll
      for (int j = 0; j < 8; ++j)
        stage16(KgS[j] + (size_t)(i + 1) * 8192, nb + oS[j]);
      cwn = cp[(size_t)(w * 8 + i + 1) * 64 + lane];
    }
    __builtin_amdgcn_sched_barrier(0);
    if (i < 7) asm volatile("s_waitcnt vmcnt(9) lgkmcnt(0)" ::: "memory");
    else       asm volatile("s_waitcnt vmcnt(0) lgkmcnt(0)" ::: "memory");
    __builtin_amdgcn_sched_barrier(0);
    const char* kcur = (i & 1) ? myb1 : myb0;
#pragma unroll
    for (int ks = 0; ks < 4; ++ks) {
      unsigned int cword = cw[ks];
      f32x4 acc;
#pragma unroll
      for (int j = 0; j < 4; ++j)
        acc[j] = __int_as_float(
            __builtin_amdgcn_ds_bpermute((cword >> (8 * j)) & 0xFF, lut_i));
      acc = MFMA16(ld8((const u16*)(kcur + ra + ks * 2048)), bq0, acc);
      acc = MFMA16(ld8((const u16*)(kcur + (ra ^ 64) + ks * 2048)), bq1, acc);
      float e0 = __builtin_amdgcn_exp2f(acc[0]);
      float e1 = __builtin_amdgcn_exp2f(acc[1]);
      float e2 = __builtin_amdgcn_exp2f(acc[2]);
      float e3 = __builtin_amdgcn_exp2f(acc[3]);
      accl += (e0 + e1) + (e2 + e3);
      asm("v_cvt_pk_bf16_f32 %0, %1, %2" : "=v"(p[i][ks * 2]) : "v"(e0), "v"(e1));
      asm("v_cvt_pk_bf16_f32 %0, %1, %2" : "=v"(p[i][ks * 2 + 1]) : "v"(e2), "v"(e3));
    }
    cw = cwn;
  }
  accl += __shfl_xor(accl, 16);
  accl += __shfl_xor(accl, 32);
  if (lane < 16) lsh[w][lane] = accl;
  __syncthreads();
  float tot = lsh[0][l15] + lsh[1][l15] + lsh[2][l15] + lsh[3][l15];
  bool zrow = (tot == 0.0f);
  float cscale = zrow ? (1.0f / 2048.0f) : (1.0f / tot);

  // ---------- pass 2: attn store + PV (no QK recompute) ----------
  f32x4 ctx[4];
#pragma unroll
  for (int i = 0; i < 4; ++i) ctx[i] = (f32x4){0.f, 0.f, 0.f, 0.f};
  float* attb = attn_out + (size_t)bh * Nn * Nn + (size_t)(q0 + l15) * Nn + wk0;

#pragma unroll
  for (int j = 0; j < 8; ++j) stage16(VgS[j], myb0 + oS[j]);

#pragma unroll
  for (int i = 0; i < 8; ++i) {
    if (i < 7) {
      char* nb = (i & 1) ? myb0 : myb1;
#pragma unroll
      for (int j = 0; j < 8; ++j)
        stage16(VgS[j] + (size_t)(i + 1) * 128, nb + oS[j]);
    }
    __builtin_amdgcn_sched_barrier(0);
    if (i == 0)     asm volatile("s_waitcnt vmcnt(8) lgkmcnt(0)" ::: "memory");
    else if (i < 7) asm volatile("s_waitcnt vmcnt(12) lgkmcnt(0)" ::: "memory");
    else            asm volatile("s_waitcnt vmcnt(4) lgkmcnt(0)" ::: "memory");
    __builtin_amdgcn_sched_barrier(0);
    const char* vcur = (i & 1) ? myb1 : myb0;

    uint pp[8];
#pragma unroll
    for (int r = 0; r < 8; ++r) pp[r] = zrow ? 0x3F803F80u : p[i][r];
    // P -> LDS (C-layout), for A-fragment re-read
#pragma unroll
    for (int ks = 0; ks < 4; ++ks) {
      int2 wv = {(int)pp[ks * 2], (int)pp[ks * 2 + 1]};
      *(int2*)(pwave + pwbase + ((ks * 32 + l4 * 8) ^ sw)) = wv;
    }
    // attn output: float(p)*cscale
#pragma unroll
    for (int ks = 0; ks < 4; ++ks) {
      uint u0 = pp[ks * 2], u1 = pp[ks * 2 + 1];
      f32x4 o;
      o[0] = __int_as_float((int)(u0 << 16)) * cscale;
      o[1] = __int_as_float((int)(u0 & 0xFFFF0000u)) * cscale;
      o[2] = __int_as_float((int)(u1 << 16)) * cscale;
      o[3] = __int_as_float((int)(u1 & 0xFFFF0000u)) * cscale;
      __builtin_nontemporal_store(o, (f32x4*)(attb + i * 64 + ks * 16 + l4 * 4));
    }
    // PV with unnormalized P
#pragma unroll
    for (int half = 0; half < 2; ++half) {
      bf16x8 pa = ld8((const u16*)(pwave + pwbase + ((half * 64 + l4 * 16) ^ sw)));
#pragma unroll
      for (int d = 0; d < 4; ++d) {
        bf16x8 v = ld8((const u16*)(vcur + d * 2048 + l15 * 128 +
                                    ((half * 64 + l4 * 16) ^ sw)));
        ctx[d] = MFMA16(pa, v, ctx[d]);
      }
    }
  }

  // per-row scale of partial ctx (rows = l4*4+j; cscale lives at lane==row)
  float csr[4];
#pragma unroll
  for (int j = 0; j < 4; ++j)
    csr[j] = __int_as_float(
        __builtin_amdgcn_ds_bpermute((l4 * 4 + j) * 4, __float_as_int(cscale)));
#pragma unroll
  for (int d = 0; d < 4; ++d)
#pragma unroll
    for (int j = 0; j < 4; ++j) ctx[d][j] *= csr[j];

  // combine partial ctx across the 4 k-split waves (reuse kvb as f32 scratch)
  __syncthreads();                       // all waves done with kvb as V
  float* creg = (float*)kvb;
  if (w > 0) {
    float* cs_ = creg + ((size_t)(w - 1) * 64 + lane) * 17;
#pragma unroll
    for (int d = 0; d < 4; ++d)
#pragma unroll
      for (int j = 0; j < 4; ++j) cs_[d * 4 + j] = ctx[d][j];
  }
  __syncthreads();
  if (w == 0) {
    float* c0 = creg + (size_t)lane * 17;
    float* c1 = creg + ((size_t)64 + lane) * 17;
    float* c2 = creg + ((size_t)128 + lane) * 17;
#pragma unroll
    for (int d = 0; d < 4; ++d) {
      int col = h * 64 + d * 16 + l15;
#pragma unroll
      for (int j = 0; j < 4; ++j) {
        float v = ctx[d][j] + c0[d * 4 + j] + c1[d * 4 + j] + c2[d * 4 + j];
        int qrow = q0 + l4 * 4 + j;
        ctx_ws[(size_t)(b * Nn + qrow) * Dd + col] = f2bf(v);
      }
    }
  }
}

// ================= out GEMM + residual + LayerNorm =================
__global__ __launch_bounds__(256) void outln_kernel(const u16* ctxb, const u16* woT,
                                                    const float* bo, const float* xf,
                                                    const float* ln_g, const float* ln_b,
                                                    float* yout) {
  __shared__ float ytile[32][257];
  __shared__ float muS[32], rvS[32];
  int bm0 = blockIdx.x * 32;
  int w = threadIdx.x >> 6, lane = threadIdx.x & 63;
  int l15 = lane & 15, l4 = lane >> 4;
  f32x4 acc[2][4];
#pragma unroll
  for (int q = 0; q < 2; ++q)
#pragma unroll
    for (int i = 0; i < 4; ++i) acc[q][i] = (f32x4){0.f, 0.f, 0.f, 0.f};
#pragma unroll
  for (int kst = 0; kst < 8; ++kst) {
    int k0 = kst * 32 + l4 * 8;
    bf16x8 a0 = ld8(ctxb + (size_t)(bm0 + l15) * 256 + k0);
    bf16x8 a1 = ld8(ctxb + (size_t)(bm0 + 16 + l15) * 256 + k0);
#pragma unroll
    for (int ds_ = 0; ds_ < 4; ++ds_) {
      bf16x8 bw = ld8(woT + (size_t)(w * 64 + ds_ * 16 + l15) * 256 + k0);
      acc[0][ds_] = MFMA16(a0, bw, acc[0][ds_]);
      acc[1][ds_] = MFMA16(a1, bw, acc[1][ds_]);
    }
  }
#pragma unroll
  for (int qs = 0; qs < 2; ++qs)
#pragma unroll
    for (int ds_ = 0; ds_ < 4; ++ds_) {
      int col = w * 64 + ds_ * 16 + l15;
      float bof = bo[col];
#pragma unroll
      for (int j = 0; j < 4; ++j) {
        int row = qs * 16 + l4 * 4 + j;
        ytile[row][col] = acc[qs][ds_][j] + bof + xf[(size_t)(bm0 + row) * 256 + col];
      }
    }
  __syncthreads();
  int row = threadIdx.x >> 3, seg = threadIdx.x & 7;
  float ps = 0.f, pq = 0.f;
#pragma unroll
  for (int c = 0; c < 32; ++c) {
    float v = ytile[row][seg * 32 + c];
    ps += v; pq += v * v;
  }
  ps += __shfl_xor(ps, 1); pq += __shfl_xor(pq, 1);
  ps += __shfl_xor(ps, 2); pq += __shfl_xor(pq, 2);
  ps += __shfl_xor(ps, 4); pq += __shfl_xor(pq, 4);
  if (seg == 0) {
    float mu = ps * (1.0f / 256.0f);
    muS[row] = mu;
    rvS[row] = rsqrtf(pq * (1.0f / 256.0f) - mu * mu + 1e-5f);
  }
  __syncthreads();
  float mu = muS[row], rv = rvS[row];
  float* yr = yout + (size_t)(bm0 + row) * 256;
#pragma unroll
  for (int c0 = 0; c0 < 32; c0 += 4) {
    int c = seg * 32 + c0;
    float4 o;
    o.x = (ytile[row][c + 0] - mu) * rv * ln_g[c + 0] + ln_b[c + 0];
    o.y = (ytile[row][c + 1] - mu) * rv * ln_g[c + 1] + ln_b[c + 1];
    o.z = (ytile[row][c + 2] - mu) * rv * ln_g[c + 2] + ln_b[c + 2];
    o.w = (ytile[row][c + 3] - mu) * rv * ln_g[c + 3] + ln_b[c + 3];
    *(float4*)(yr + c) = o;
  }
}

extern "C" void kernel_launch(void* const* d_in, const int* in_sizes, int n_in,
                              void* d_out, int out_size, void* d_ws, size_t ws_size,
                              hipStream_t stream) {
  const float* nodes = (const float*)d_in[0];
  const int* node_types = (const int*)d_in[1];
  const int* edge_types = (const int*)d_in[2];
  const float* adjacency = (const float*)d_in[3];
  const float* nte = (const float*)d_in[4];
  const float* ee = (const float*)d_in[5];
  const float* Wq = (const float*)d_in[6];
  const float* bq = (const float*)d_in[7];
  const float* Wk = (const float*)d_in[8];
  const float* bk = (const float*)d_in[9];
  const float* Wv = (const float*)d_in[10];
  const float* bv = (const float*)d_in[11];
  const float* Wo = (const float*)d_in[12];
  const float* bo = (const float*)d_in[13];
  const float* ln_g = (const float*)d_in[14];
  const float* ln_b = (const float*)d_in[15];

  float* y = (float*)d_out;
  float* attn = y + (size_t)Bsz * Nn * Dd;

  char* ws = (char*)d_ws;
  float* xf = (float*)(ws + OFF_X);
  u16* xbf = (u16*)(ws + OFF_XBF);
  u16* wqkvT = (u16*)(ws + OFF_WQKVT);
  u16* woT = (u16*)(ws + OFF_WOT);
  float* bqkv = (float*)(ws + OFF_BQKV);
  u16* Qb = (u16*)(ws + OFF_Q);
  u16* Kb = (u16*)(ws + OFF_K);
  u16* Vtb = (u16*)(ws + OFF_VT);
  u16* ctxb = (u16*)(ws + OFF_CTX);
  u8* codes = (u8*)(ws + OFF_CODES);

  pack_kernel<<<1027, 256, 0, stream>>>(Wq, Wk, Wv, Wo, bq, bk, bv, wqkvT, woT, bqkv);
  embed_kernel<<<2048, 256, 0, stream>>>(nodes, node_types, nte, xf, xbf);
  maskpack_kernel<<<4096, 256, 0, stream>>>(node_types, edge_types, adjacency, codes);
  qkv_kernel<<<dim3(12, 128), 256, 0, stream>>>(xbf, wqkvT, bqkv, Qb, Kb, Vtb);
  attn_kernel<<<2048, 256, 0, stream>>>(Qb, Kb, Vtb, codes, ee, attn, ctxb);
  outln_kernel<<<256, 256, 0, stream>>>(ctxb, woT, bo, xf, ln_g, ln_b, y);
}